// Round 12
// baseline (2943.089 us; speedup 1.0000x reference)
//
#include <hip/hip_runtime.h>
#include <hip/hip_bf16.h>
#include <math.h>

#define D 512
#define NHEAD 16
#define DK 32
#define NLAYER 16
#define FF 1024
#define VOC 32768
#define TTF 384
#define NCORE 256
#define NB 16

typedef __attribute__((ext_vector_type(8))) short bfrag;   // 8 bf16 (4 VGPRs)
typedef __attribute__((ext_vector_type(4))) float f32x4;

// ---------- async global->LDS, 16B per lane ----------
typedef __attribute__((address_space(3))) void lds_void;
typedef const __attribute__((address_space(1))) void gbl_void;
__device__ __forceinline__ void gload16(const void* g, void* l) {
    __builtin_amdgcn_global_load_lds((gbl_void*)g, (lds_void*)l, 16, 0, 0);
}

__device__ __forceinline__ float gelu_f(float v) {
    return 0.5f * v * (1.0f + erff(v * 0.70710678118654752f));
}

__device__ __forceinline__ void bf8_to_f32(uint4 u, float* v) {
    const __hip_bfloat16* t = reinterpret_cast<const __hip_bfloat16*>(&u);
    #pragma unroll
    for (int e = 0; e < 8; e++) v[e] = __bfloat162float(t[e]);
}
__device__ __forceinline__ uint4 f32_to_bf8(const float* v) {
    uint4 u; __hip_bfloat16* t = reinterpret_cast<__hip_bfloat16*>(&u);
    #pragma unroll
    for (int e = 0; e < 8; e++) t[e] = __float2bfloat16(v[e]);
    return u;
}

// ---------------- all weights f32 -> bf16 in ONE launch ----------------
__global__ __launch_bounds__(256) void cvtall_k(
    const float* s0, const float* s1, const float* s2, const float* s3,
    const float* s4, const float* s5, const float* s6, const float* s7,
    const float* s8, const float* s9, const float* s10,
    __hip_bfloat16* __restrict__ out)
{
    long long i = ((long long)blockIdx.x * 256 + threadIdx.x) * 8;
    if (i >= 52559872LL) return;
    const float* src; long long base; bool pad = false;
    if      (i < 12582912LL) { src = s0;  base = 0LL; }
    else if (i < 16777216LL) { src = s1;  base = 12582912LL; }
    else if (i < 25165824LL) { src = s2;  base = 16777216LL; }
    else if (i < 33554432LL) { src = s3;  base = 25165824LL; }
    else if (i < 50331648LL) { src = s4;  base = 33554432LL; }
    else if (i < 51118080LL) { src = s5;  base = 50331648LL; }
    else if (i < 51904512LL) { src = s6;  base = 51118080LL; }
    else if (i < 52166656LL) { src = s7;  base = 51904512LL; }
    else if (i < 52428800LL) { src = s8;  base = 52166656LL; }
    else if (i < 52494336LL) { src = s9;  base = 52428800LL; pad = true; }
    else                     { src = s10; base = 52494336LL; pad = true; }
    long long loc = i - base;
    float v[8] = {0.f,0.f,0.f,0.f,0.f,0.f,0.f,0.f};
    if (!pad || loc < 32768LL) {
        float4 a = *reinterpret_cast<const float4*>(src + loc);
        float4 b = *reinterpret_cast<const float4*>(src + loc + 4);
        v[0]=a.x; v[1]=a.y; v[2]=a.z; v[3]=a.w; v[4]=b.x; v[5]=b.y; v[6]=b.z; v[7]=b.w;
    }
    *reinterpret_cast<uint4*>(out + i) = f32_to_bf8(v);
}

// ---------------- all three embedding gathers in ONE launch ----------------
// blocks x: [0,512) lg -> lg_dst (rows b*512+t); [512,768) md -> md_dst (rows b*256+t');
// [768,1024) core -> x rows b*TTF + 128 + t''.
__global__ __launch_bounds__(128) void embed_all_k(
    const int* __restrict__ ids,
    const float* __restrict__ lg_sem, const float* __restrict__ lg_pos,
    const float* __restrict__ md_sem, const float* __restrict__ md_pos,
    const float* __restrict__ em_sem, const float* __restrict__ em_pos,
    __hip_bfloat16* __restrict__ lg_dst, __hip_bfloat16* __restrict__ md_dst,
    __hip_bfloat16* __restrict__ x)
{
    int bx = blockIdx.x, b = blockIdx.y, tid = threadIdx.x;
    const float *sem, *pos;
    __hip_bfloat16* outp;
    int t, idoff;
    if (bx < 512)      { t = bx;       sem = lg_sem; pos = lg_pos; idoff = 0;   outp = lg_dst + (size_t)(b * 512 + t) * D; }
    else if (bx < 768) { t = bx - 512; sem = md_sem; pos = md_pos; idoff = 512; outp = md_dst + (size_t)(b * 256 + t) * D; }
    else               { t = bx - 768; sem = em_sem; pos = em_pos; idoff = 768; outp = x + (size_t)(b * TTF + 128 + t) * D; }
    int id = ids[b * 1024 + idoff + t];
    float4 a = reinterpret_cast<const float4*>(sem + (size_t)id * D)[tid];
    float4 p = reinterpret_cast<const float4*>(pos + (size_t)t * D)[tid];
    __hip_bfloat16* o = outp + tid * 4;
    o[0] = __float2bfloat16(a.x + p.x); o[1] = __float2bfloat16(a.y + p.y);
    o[2] = __float2bfloat16(a.z + p.z); o[3] = __float2bfloat16(a.w + p.w);
}

// ---------------- bf16 MFMA GEMM: C(M,N) = A(M,K) @ W(N,K)^T + bias ----------------
// 128x128 tile, 4 waves, BK=64, double-buffered LDS, XOR-swizzled, RT row-tiles per
// block as one flattened continuous pipeline. At row-tile boundaries vmcnt(63) (not 8):
// vmcnt retires in order (m135), so the 8 needed loads are the oldest — no need to
// drain the 64 epilogue stores sitting between them and the newly staged loads.
// flags: 0=f32 out, 2=bf16+GELU, 3=bf16, 4=bf16 += (fused residual RMW)
// order 0: XCD-chunk row-major. order 1: col-tile-major.
__global__ __launch_bounds__(256) void mgemm_k(
    const __hip_bfloat16* __restrict__ A, const __hip_bfloat16* __restrict__ W,
    const float* __restrict__ bias, void* __restrict__ C,
    int M, int N, int K, int flags, int order, int RT)
{
    __shared__ __align__(16) __hip_bfloat16 sA[2][8192];
    __shared__ __align__(16) __hip_bfloat16 sB[2][8192];
    int tid = threadIdx.x;
    int w = tid >> 6, lane = tid & 63;
    int wr = w >> 1, wc = w & 1;

    int nbx = gridDim.x, nby = gridDim.y;
    int nwg = nbx * nby;
    int bid0 = blockIdx.y * nbx + blockIdx.x;
    int bid = bid0;
    if (nwg >= 8) {                        // bijective XCD swizzle (m204)
        int q = nwg >> 3, r = nwg & 7;
        int xcd = bid0 & 7, lb = bid0 >> 3;
        bid = (xcd < r ? xcd * (q + 1) : r * (q + 1) + (xcd - r) * q) + lb;
    }
    int bx, byg;
    if (order == 1) { bx = bid / nby; byg = bid - bx * nby; }
    else            { byg = bid / nbx; bx = bid - byg * nbx; }
    int col0 = bx * 128;

    int srow = lane >> 3;
    int scg  = (lane & 7) ^ srow;
    int cr = lane >> 4;
    int cc = lane & 15;

    auto stage = [&](int buf, int t, int k0) {
        int r0 = (byg * RT + t) * 128;
        #pragma unroll
        for (int r = 0; r < 4; r++) {
            int blk = r * 4 + w;
            const __hip_bfloat16* pa = A + (size_t)(r0 + blk * 8 + srow) * K + scg * 8 + k0;
            const __hip_bfloat16* pb = W + (size_t)(col0 + blk * 8 + srow) * K + scg * 8 + k0;
            gload16(pa, &sA[buf][blk * 512]);
            gload16(pb, &sB[buf][blk * 512]);
        }
    };

    int ksteps = K >> 6;
    int tsteps = RT * ksteps;

    stage(0, 0, 0);
    for (int t = 0; t < RT; t++) {
        int row0 = (byg * RT + t) * 128;

        f32x4 acc[4][4];
        #pragma unroll
        for (int m = 0; m < 4; m++)
            #pragma unroll
            for (int n = 0; n < 4; n++) acc[m][n] = (f32x4){0.f, 0.f, 0.f, 0.f};

        for (int kk = 0; kk < ksteps; kk++) {
            int s = t * ksteps + kk;
            int p = s & 1;
            if (s + 1 < tsteps) {
                int ns = s + 1;
                stage(p ^ 1, ns / ksteps, (ns % ksteps) << 6);
                if (kk == 0 && t > 0) {
                    // boundary: 8 needed loads are oldest; skip draining epilogue stores
                    asm volatile("s_waitcnt vmcnt(63)" ::: "memory");
                } else {
                    asm volatile("s_waitcnt vmcnt(8)" ::: "memory");
                }
            } else {
                asm volatile("s_waitcnt vmcnt(0)" ::: "memory");
            }
            __builtin_amdgcn_sched_barrier(0);
            __builtin_amdgcn_s_barrier();
            __builtin_amdgcn_sched_barrier(0);

            #pragma unroll
            for (int ks = 0; ks < 2; ks++) {
                bfrag af[4], bf[4];
                #pragma unroll
                for (int m = 0; m < 4; m++) {
                    int blk = wr * 8 + m * 2 + (cc >> 3);
                    int slot = (ks * 4 + cr) ^ (cc & 7);
                    af[m] = *reinterpret_cast<const bfrag*>(&sA[p][blk * 512 + (cc & 7) * 64 + slot * 8]);
                }
                #pragma unroll
                for (int n = 0; n < 4; n++) {
                    int blk = wc * 8 + n * 2 + (cc >> 3);
                    int slot = (ks * 4 + cr) ^ (cc & 7);
                    bf[n] = *reinterpret_cast<const bfrag*>(&sB[p][blk * 512 + (cc & 7) * 64 + slot * 8]);
                }
                #pragma unroll
                for (int m = 0; m < 4; m++)
                    #pragma unroll
                    for (int n = 0; n < 4; n++)
                        acc[m][n] = __builtin_amdgcn_mfma_f32_16x16x32_bf16(af[m], bf[n], acc[m][n], 0, 0, 0);
            }
            __builtin_amdgcn_sched_barrier(0);
            __builtin_amdgcn_s_barrier();
            __builtin_amdgcn_sched_barrier(0);
        }

        #pragma unroll
        for (int m = 0; m < 4; m++) {
            int rg = row0 + wr * 64 + m * 16 + cr * 4;
            #pragma unroll
            for (int n = 0; n < 4; n++) {
                int cg = col0 + wc * 64 + n * 16 + cc;
                float bs = bias[cg];
                #pragma unroll
                for (int j = 0; j < 4; j++) {
                    float v = acc[m][n][j] + bs;
                    size_t off = (size_t)(rg + j) * N + cg;
                    if (flags == 2)      ((__hip_bfloat16*)C)[off] = __float2bfloat16(gelu_f(v));
                    else if (flags == 3) ((__hip_bfloat16*)C)[off] = __float2bfloat16(v);
                    else if (flags == 4) {
                        __hip_bfloat16* cp = (__hip_bfloat16*)C + off;
                        *cp = __float2bfloat16(v + __bfloat162float(*cp));
                    }
                    else                 ((float*)C)[off] = v;
                }
            }
        }
    }
}

// ---------------- layernorm, vectorized; IB/OB: 0=f32, 1=bf16 ----------------
template<int IB, int OB>
__global__ __launch_bounds__(256) void ln_k(
    const void* __restrict__ in, void* __restrict__ out,
    const float* __restrict__ g, const float* __restrict__ bt,
    int rpb, int in_stride, int in_off, int out_stride, int out_off)
{
    int r = blockIdx.x * 4 + (threadIdx.x >> 6);
    int b = r / rpb, t = r % rpb;
    size_t irow = (size_t)(b * in_stride + in_off + t) * D;
    size_t orow = (size_t)(b * out_stride + out_off + t) * D;
    int c0 = (threadIdx.x & 63) * 8;
    float v[8];
    if (IB) {
        bf8_to_f32(*reinterpret_cast<const uint4*>((const __hip_bfloat16*)in + irow + c0), v);
    } else {
        float4 a = *reinterpret_cast<const float4*>((const float*)in + irow + c0);
        float4 bq = *reinterpret_cast<const float4*>((const float*)in + irow + c0 + 4);
        v[0]=a.x; v[1]=a.y; v[2]=a.z; v[3]=a.w; v[4]=bq.x; v[5]=bq.y; v[6]=bq.z; v[7]=bq.w;
    }
    float s = 0.f;
    #pragma unroll
    for (int e = 0; e < 8; e++) s += v[e];
    #pragma unroll
    for (int off = 32; off; off >>= 1) s += __shfl_xor(s, off);
    float mu = s * (1.f / 512.f);
    float vs = 0.f;
    #pragma unroll
    for (int e = 0; e < 8; e++) { float d = v[e] - mu; vs += d * d; }
    #pragma unroll
    for (int off = 32; off; off >>= 1) vs += __shfl_xor(vs, off);
    float rstd = rsqrtf(vs * (1.f / 512.f) + 1e-5f);
    float y[8];
    #pragma unroll
    for (int e = 0; e < 8; e++) y[e] = (v[e] - mu) * rstd * g[c0 + e] + bt[c0 + e];
    if (OB) {
        *reinterpret_cast<uint4*>((__hip_bfloat16*)out + orow + c0) = f32_to_bf8(y);
    } else {
        *reinterpret_cast<float4*>((float*)out + orow + c0)     = make_float4(y[0], y[1], y[2], y[3]);
        *reinterpret_cast<float4*>((float*)out + orow + c0 + 4) = make_float4(y[4], y[5], y[6], y[7]);
    }
}

// ---------------- fused MFMA causal attention (core layers) ----------------
// Split 2 ways per (h,b): part 0 = q-tiles 0..15 (keys 0..255), part 1 = q-tiles 16..23.
__global__ __launch_bounds__(512) void fattn_k(
    const __hip_bfloat16* __restrict__ qkv, __hip_bfloat16* __restrict__ o)
{
    __shared__ __align__(16) __hip_bfloat16 Kl[24 * 512];
    __shared__ __align__(16) __hip_bfloat16 Vl[24 * 512];
    __shared__ __align__(16) __hip_bfloat16 Pl[8 * 512];
    int h = blockIdx.x, b = blockIdx.y, part = blockIdx.z;
    int tid = threadIdx.x, w = tid >> 6, l = tid & 63;
    const size_t base = (size_t)b * TTF * 1536 + h * DK;

    int niter = part ? 3 : 2;
    for (int it = 0; it < niter; it++) {
        int item = it * 512 + tid;
        int key = item >> 2, dg = item & 3;
        uint4 k4 = *reinterpret_cast<const uint4*>(qkv + base + (size_t)key * 1536 + 512 + dg * 8);
        *reinterpret_cast<uint4*>(&Kl[((key >> 4) * 64 + dg * 16 + (key & 15)) * 8]) = k4;
        uint4 v4 = *reinterpret_cast<const uint4*>(qkv + base + (size_t)key * 1536 + 1024 + dg * 8);
        const ushort* ve = reinterpret_cast<const ushort*>(&v4);
        #pragma unroll
        for (int e = 0; e < 8; e++) {
            int dk = dg * 8 + e;
            int f = (((key & 31) >> 3) << 4) | (dk & 15);
            int idx = (((key >> 5) << 1) + (dk >> 4)) * 512 + f * 8 + (key & 7);
            reinterpret_cast<ushort*>(Vl)[idx] = ve[e];
        }
    }
    __syncthreads();

    const float sc = 0.17677669529663687f;
    __hip_bfloat16* pw = Pl + w * 512;

    int niq = part ? 1 : 2;
    for (int iq = 0; iq < niq; iq++) {
        int qt = part ? (16 + w) : (iq == 0 ? w : 15 - w);
        int q0 = qt * 16;
        bfrag qf = *reinterpret_cast<const bfrag*>(qkv + base + (size_t)(q0 + (l & 15)) * 1536 + (l >> 4) * 8);
        f32x4 oa0 = (f32x4){0.f, 0.f, 0.f, 0.f};
        f32x4 oa1 = (f32x4){0.f, 0.f, 0.f, 0.f};
        float mrun[4], lrun[4];
        #pragma unroll
        for (int jj = 0; jj < 4; jj++) { mrun[jj] = -3.0e38f; lrun[jj] = 0.f; }
        int ksmax = (q0 + 15) >> 5;

        for (int ks = 0; ks <= ksmax; ks++) {
            bfrag kf0 = *reinterpret_cast<const bfrag*>(&Kl[(ks * 2 + 0) * 512 + l * 8]);
            bfrag kf1 = *reinterpret_cast<const bfrag*>(&Kl[(ks * 2 + 1) * 512 + l * 8]);
            f32x4 z = (f32x4){0.f, 0.f, 0.f, 0.f};
            __builtin_amdgcn_s_setprio(1);
            f32x4 s0 = __builtin_amdgcn_mfma_f32_16x16x32_bf16(qf, kf0, z, 0, 0, 0);
            f32x4 s1 = __builtin_amdgcn_mfma_f32_16x16x32_bf16(qf, kf1, z, 0, 0, 0);
            __builtin_amdgcn_s_setprio(0);
            if (ks == ksmax) {
                #pragma unroll
                for (int jj = 0; jj < 4; jj++) {
                    int q = q0 + ((l >> 4) << 2) + jj;
                    if (ks * 32 + (l & 15) > q)      s0[jj] = -3.0e38f;
                    if (ks * 32 + 16 + (l & 15) > q) s1[jj] = -3.0e38f;
                }
            }
            float p0[4], p1[4], ps[4];
            #pragma unroll
            for (int jj = 0; jj < 4; jj++) {
                float sm = fmaxf(s0[jj], s1[jj]);
                #pragma unroll
                for (int off = 1; off <= 8; off <<= 1) sm = fmaxf(sm, __shfl_xor(sm, off));
                float mnew = fmaxf(mrun[jj], sm);
                float f = __expf((mrun[jj] - mnew) * sc);
                mrun[jj] = mnew;
                lrun[jj] *= f;
                oa0[jj] *= f; oa1[jj] *= f;
                p0[jj] = __expf((s0[jj] - mnew) * sc);
                p1[jj] = __expf((s1[jj] - mnew) * sc);
                ps[jj] = p0[jj] + p1[jj];
            }
            #pragma unroll
            for (int jj = 0; jj < 4; jj++) {
                float t = ps[jj];
                #pragma unroll
                for (int off = 1; off <= 8; off <<= 1) t += __shfl_xor(t, off);
                lrun[jj] += t;
            }
            #pragma unroll
            for (int jj = 0; jj < 4; jj++) {
                int ql = ((l >> 4) << 2) + jj;
                int kl0 = l & 15, kl1 = 16 + (l & 15);
                pw[((kl0 >> 3) * 16 + ql) * 8 + (kl0 & 7)] = __float2bfloat16(p0[jj]);
                pw[((kl1 >> 3) * 16 + ql) * 8 + (kl1 & 7)] = __float2bfloat16(p1[jj]);
            }
            bfrag pf  = *reinterpret_cast<const bfrag*>(&pw[l * 8]);
            bfrag vf0 = *reinterpret_cast<const bfrag*>(&Vl[(ks * 2 + 0) * 512 + l * 8]);
            bfrag vf1 = *reinterpret_cast<const bfrag*>(&Vl[(ks * 2 + 1) * 512 + l * 8]);
            __builtin_amdgcn_s_setprio(1);
            oa0 = __builtin_amdgcn_mfma_f32_16x16x32_bf16(pf, vf0, oa0, 0, 0, 0);
            oa1 = __builtin_amdgcn_mfma_f32_16x16x32_bf16(pf, vf1, oa1, 0, 0, 0);
            __builtin_amdgcn_s_setprio(0);
        }
        #pragma unroll
        for (int jj = 0; jj < 4; jj++) {
            float inv = 1.0f / lrun[jj];
            int q = q0 + ((l >> 4) << 2) + jj;
            size_t orow = ((size_t)b * TTF + q) * D + h * DK;
            o[orow + (l & 15)]      = __float2bfloat16(oa0[jj] * inv);
            o[orow + 16 + (l & 15)] = __float2bfloat16(oa1[jj] * inv);
        }
    }
}

// ---------------- summarizer cross-attention: MFMA, block per (h,b), 4 waves ----------------
template<int TLEN>
__global__ __launch_bounds__(256) void sattn_k(
    const __hip_bfloat16* __restrict__ q, const __hip_bfloat16* __restrict__ kv,
    __hip_bfloat16* __restrict__ o)
{
    __shared__ __align__(16) __hip_bfloat16 Kl[(TLEN / 16) * 512];
    __shared__ __align__(16) __hip_bfloat16 Vl[(TLEN / 16) * 512];
    __shared__ __align__(16) __hip_bfloat16 Pl[4 * 512];
    int h = blockIdx.x, b = blockIdx.y;
    int tid = threadIdx.x, w = tid >> 6, l = tid & 63;

    for (int it = 0; it < TLEN / 64; it++) {
        int item = it * 256 + tid;
        int key = item >> 2, dg = item & 3;
        const __hip_bfloat16* kr = kv + (size_t)(b * TLEN + key) * 1024 + h * DK + dg * 8;
        uint4 k4 = *reinterpret_cast<const uint4*>(kr);
        *reinterpret_cast<uint4*>(&Kl[((key >> 4) * 64 + dg * 16 + (key & 15)) * 8]) = k4;
        uint4 v4 = *reinterpret_cast<const uint4*>(kr + 512);
        const ushort* ve = reinterpret_cast<const ushort*>(&v4);
        #pragma unroll
        for (int e = 0; e < 8; e++) {
            int dk = dg * 8 + e;
            int f = (((key & 31) >> 3) << 4) | (dk & 15);
            int idx = (((key >> 5) << 1) + (dk >> 4)) * 512 + f * 8 + (key & 7);
            reinterpret_cast<ushort*>(Vl)[idx] = ve[e];
        }
    }
    __syncthreads();

    const float sc = 0.17677669529663687f;
    __hip_bfloat16* pw = Pl + w * 512;
    int q0 = w * 16;
    bfrag qf = *reinterpret_cast<const bfrag*>(q + (size_t)(q0 + (l & 15)) * D + h * DK + (l >> 4) * 8);
    f32x4 oa0 = (f32x4){0.f, 0.f, 0.f, 0.f};
    f32x4 oa1 = (f32x4){0.f, 0.f, 0.f, 0.f};
    float mrun[4], lrun[4];
    #pragma unroll
    for (int jj = 0; jj < 4; jj++) { mrun[jj] = -3.0e38f; lrun[jj] = 0.f; }

    for (int ks = 0; ks < TLEN / 32; ks++) {
        bfrag kf0 = *reinterpret_cast<const bfrag*>(&Kl[(ks * 2 + 0) * 512 + l * 8]);
        bfrag kf1 = *reinterpret_cast<const bfrag*>(&Kl[(ks * 2 + 1) * 512 + l * 8]);
        f32x4 z = (f32x4){0.f, 0.f, 0.f, 0.f};
        __builtin_amdgcn_s_setprio(1);
        f32x4 s0 = __builtin_amdgcn_mfma_f32_16x16x32_bf16(qf, kf0, z, 0, 0, 0);
        f32x4 s1 = __builtin_amdgcn_mfma_f32_16x16x32_bf16(qf, kf1, z, 0, 0, 0);
        __builtin_amdgcn_s_setprio(0);
        float p0[4], p1[4], ps[4];
        #pragma unroll
        for (int jj = 0; jj < 4; jj++) {
            float sm = fmaxf(s0[jj], s1[jj]);
            #pragma unroll
            for (int off = 1; off <= 8; off <<= 1) sm = fmaxf(sm, __shfl_xor(sm, off));
            float mnew = fmaxf(mrun[jj], sm);
            float f = __expf((mrun[jj] - mnew) * sc);
            mrun[jj] = mnew;
            lrun[jj] *= f;
            oa0[jj] *= f; oa1[jj] *= f;
            p0[jj] = __expf((s0[jj] - mnew) * sc);
            p1[jj] = __expf((s1[jj] - mnew) * sc);
            ps[jj] = p0[jj] + p1[jj];
        }
        #pragma unroll
        for (int jj = 0; jj < 4; jj++) {
            float t = ps[jj];
            #pragma unroll
            for (int off = 1; off <= 8; off <<= 1) t += __shfl_xor(t, off);
            lrun[jj] += t;
        }
        #pragma unroll
        for (int jj = 0; jj < 4; jj++) {
            int ql = ((l >> 4) << 2) + jj;
            int kl0 = l & 15, kl1 = 16 + (l & 15);
            pw[((kl0 >> 3) * 16 + ql) * 8 + (kl0 & 7)] = __float2bfloat16(p0[jj]);
            pw[((kl1 >> 3) * 16 + ql) * 8 + (kl1 & 7)] = __float2bfloat16(p1[jj]);
        }
        bfrag pf  = *reinterpret_cast<const bfrag*>(&pw[l * 8]);
        bfrag vf0 = *reinterpret_cast<const bfrag*>(&Vl[(ks * 2 + 0) * 512 + l * 8]);
        bfrag vf1 = *reinterpret_cast<const bfrag*>(&Vl[(ks * 2 + 1) * 512 + l * 8]);
        __builtin_amdgcn_s_setprio(1);
        oa0 = __builtin_amdgcn_mfma_f32_16x16x32_bf16(pf, vf0, oa0, 0, 0, 0);
        oa1 = __builtin_amdgcn_mfma_f32_16x16x32_bf16(pf, vf1, oa1, 0, 0, 0);
        __builtin_amdgcn_s_setprio(0);
    }
    #pragma unroll
    for (int jj = 0; jj < 4; jj++) {
        float inv = 1.0f / lrun[jj];
        int qi = q0 + ((l >> 4) << 2) + jj;
        size_t orow = ((size_t)b * 64 + qi) * D + h * DK;
        o[orow + (l & 15)]      = __float2bfloat16(oa0[jj] * inv);
        o[orow + 16 + (l & 15)] = __float2bfloat16(oa1[jj] * inv);
    }
}

// ---------------- tgt copy ----------------
__global__ __launch_bounds__(256) void tgt_k(const int* __restrict__ tids, float* __restrict__ out)
{
    int i = blockIdx.x * 256 + threadIdx.x;
    int b = i >> 8, c = i & 255;
    out[i] = (float)tids[b * 1024 + 768 + c];
}

extern "C" void kernel_launch(void* const* d_in, const int* in_sizes, int n_in,
                              void* d_out, int out_size, void* d_ws, size_t ws_size,
                              hipStream_t stream) {
    (void)in_sizes; (void)n_in; (void)out_size; (void)ws_size;
    const int*   input_ids  = (const int*)  d_in[0];
    const int*   target_ids = (const int*)  d_in[1];
    const float* emb_sem    = (const float*)d_in[2];
    const float* emb_pos    = (const float*)d_in[3];
    const float* lg_sem     = (const float*)d_in[4];
    const float* lg_pos     = (const float*)d_in[5];
    const float* lg_inw     = (const float*)d_in[6];
    const float* lg_inb     = (const float*)d_in[7];
    const float* lg_outw    = (const float*)d_in[8];
    const float* lg_outb    = (const float*)d_in[9];
    const float* lg_tok     = (const float*)d_in[10];
    const float* lg_lng     = (const float*)d_in[11];
    const float* lg_lnb     = (const float*)d_in[12];
    const float* md_sem     = (const float*)d_in[13];
    const float* md_pos     = (const float*)d_in[14];
    const float* md_inw     = (const float*)d_in[15];
    const float* md_inb     = (const float*)d_in[16];
    const float* md_outw    = (const float*)d_in[17];
    const float* md_outb    = (const float*)d_in[18];
    const float* md_tok     = (const float*)d_in[19];
    const float* md_lng     = (const float*)d_in[20];
    const float* md_lnb     = (const float*)d_in[21];
    const float* qkv_w      = (const float*)d_in[22];
    const float* qkv_b      = (const float*)d_in[23];
    const float* wo_w       = (const float*)d_in[24];
    const float* wo_b       = (const float*)d_in[25];
    const float* ln1_g      = (const float*)d_in[26];
    const float* ln1_b      = (const float*)d_in[27];
    const float* ln2_g      = (const float*)d_in[28];
    const float* ln2_b      = (const float*)d_in[29];
    const float* ff1_w      = (const float*)d_in[30];
    const float* ff1_b      = (const float*)d_in[31];
    const float* ff2_w      = (const float*)d_in[32];
    const float* ff2_b      = (const float*)d_in[33];
    const float* hd_lng     = (const float*)d_in[34];
    const float* hd_lnb     = (const float*)d_in[35];
    const float* hd_w       = (const float*)d_in[36];
    const float* hd_b       = (const float*)d_in[37];

    // ---- workspace layout (bf16 unless noted) ----
    __hip_bfloat16* x_bf   = (__hip_bfloat16*)d_ws;            // 3,145,728 (residual stream)
    __hip_bfloat16* h_bf   = x_bf   + 3145728;                 // 3,145,728
    __hip_bfloat16* d_bf   = h_bf   + 3145728;                 // 3,145,728 (unused, layout stability)
    __hip_bfloat16* a_bf   = d_bf   + 3145728;                 // 6,291,456 (lg embeds | md embeds @+4194304; later attn out)
    __hip_bfloat16* qkv_bf = a_bf   + 6291456;                 // 9,437,184
    __hip_bfloat16* sumo_bf= qkv_bf + 9437184;                 // 524,288
    __hip_bfloat16* w_qkv  = sumo_bf+ 524288;                  // 12,582,912   -- cvtall region start
    __hip_bfloat16* w_wo   = w_qkv  + 12582912;                // 4,194,304
    __hip_bfloat16* w_ff1  = w_wo   + 4194304;                 // 8,388,608
    __hip_bfloat16* w_ff2  = w_ff1  + 8388608;                 // 8,388,608
    __hip_bfloat16* w_hd   = w_ff2  + 8388608;                 // 16,777,216
    __hip_bfloat16* w_lgin = w_hd   + 16777216;                // 786,432
    __hip_bfloat16* w_mdin = w_lgin + 786432;                  // 786,432
    __hip_bfloat16* w_lgout= w_mdin + 786432;                  // 262,144
    __hip_bfloat16* w_mdout= w_lgout+ 262144;                  // 262,144
    __hip_bfloat16* tok_lg = w_mdout+ 262144;                  // 65,536 (32768 valid + zero pad)
    __hip_bfloat16* tok_md = tok_lg + 65536;                   // 65,536       -- cvtall region end
    __hip_bfloat16* q_bf   = tok_md + 65536;                   // 65,536
    float* so2 = (float*)(q_bf + 65536);                       // 524,288 f32

    // ---- all weight conversions in one launch ----
    cvtall_k<<<25664, 256, 0, stream>>>(qkv_w, wo_w, ff1_w, ff2_w, hd_w,
                                        lg_inw, md_inw, lg_outw, md_outw,
                                        lg_tok, md_tok, w_qkv);

    // ---- all embeddings in one launch (lg -> a_bf, md -> a_bf+4194304, core -> x) ----
    embed_all_k<<<dim3(1024, NB), 128, 0, stream>>>(input_ids,
        lg_sem, lg_pos, md_sem, md_pos, emb_sem, emb_pos,
        a_bf, a_bf + 4194304, x_bf);

    // ======== summarizer LG (tlen=512) ========
    mgemm_k<<<dim3(8, 64), 256, 0, stream>>>(a_bf, w_lgin + 512 * 512, lg_inb + 512, qkv_bf, 8192, 1024, 512, 3, 0, 1);
    mgemm_k<<<dim3(4, 1), 256, 0, stream>>>(tok_lg, w_lgin, lg_inb, q_bf, 128, 512, 512, 3, 0, 1);
    sattn_k<512><<<dim3(NHEAD, NB), 256, 0, stream>>>(q_bf, qkv_bf, sumo_bf);
    mgemm_k<<<dim3(4, 8), 256, 0, stream>>>(sumo_bf, w_lgout, lg_outb, so2, 1024, 512, 512, 0, 0, 1);
    ln_k<0, 1><<<256, 256, 0, stream>>>(so2, x_bf, lg_lng, lg_lnb, 64, 64, 0, TTF, 0);

    // ======== summarizer MD (tlen=256) ========
    mgemm_k<<<dim3(8, 32), 256, 0, stream>>>(a_bf + 4194304, w_mdin + 512 * 512, md_inb + 512, qkv_bf, 4096, 1024, 512, 3, 0, 1);
    mgemm_k<<<dim3(4, 1), 256, 0, stream>>>(tok_md, w_mdin, md_inb, q_bf, 128, 512, 512, 3, 0, 1);
    sattn_k<256><<<dim3(NHEAD, NB), 256, 0, stream>>>(q_bf, qkv_bf, sumo_bf);
    mgemm_k<<<dim3(4, 8), 256, 0, stream>>>(sumo_bf, w_mdout, md_outb, so2, 1024, 512, 512, 0, 0, 1);
    ln_k<0, 1><<<256, 256, 0, stream>>>(so2, x_bf, md_lng, md_lnb, 64, 64, 0, TTF, 64);

    // ======== 16 transformer layers (bf16 residual, residual fused into GEMM epilogue) ========
    ln_k<1, 1><<<1536, 256, 0, stream>>>(x_bf, h_bf, ln1_g, ln1_b, TTF, TTF, 0, TTF, 0);
    for (int l = 0; l < NLAYER; l++) {
        mgemm_k<<<dim3(12, 48), 256, 0, stream>>>(h_bf, w_qkv + (size_t)l * 1536 * 512, qkv_b + l * 1536, qkv_bf, 6144, 1536, 512, 3, 0, 1);
        fattn_k<<<dim3(NHEAD, NB, 2), 512, 0, stream>>>(qkv_bf, a_bf);
        mgemm_k<<<dim3(4, 48), 256, 0, stream>>>(a_bf, w_wo + (size_t)l * 512 * 512, wo_b + l * D, x_bf, 6144, 512, 512, 4, 0, 1);
        ln_k<1, 1><<<1536, 256, 0, stream>>>(x_bf, h_bf, ln2_g + l * D, ln2_b + l * D, TTF, TTF, 0, TTF, 0);
        mgemm_k<<<dim3(8, 48), 256, 0, stream>>>(h_bf, w_ff1 + (size_t)l * 1024 * 512, ff1_b + l * FF, a_bf, 6144, 1024, 512, 2, 0, 1);
        mgemm_k<<<dim3(4, 48), 256, 0, stream>>>(a_bf, w_ff2 + (size_t)l * 512 * 1024, ff2_b + l * D, x_bf, 6144, 512, 1024, 4, 0, 1);
        if (l < NLAYER - 1) {
            ln_k<1, 1><<<1536, 256, 0, stream>>>(x_bf, h_bf, ln1_g + (size_t)(l + 1) * D, ln1_b + (size_t)(l + 1) * D, TTF, TTF, 0, TTF, 0);
        }
    }

    // ======== head: LN + col-tile-major GEMM, RT=8 continuous pipeline ========
    ln_k<1, 1><<<1024, 256, 0, stream>>>(x_bf, h_bf, hd_lng, hd_lnb, NCORE, TTF, 128, NCORE, 0);
    float* logits = (float*)d_out;
    mgemm_k<<<dim3(256, 4), 256, 0, stream>>>(h_bf, w_hd, hd_b, logits, 4096, VOC, 512, 0, 1, 8);
    tgt_k<<<16, 256, 0, stream>>>(target_ids, logits + (size_t)NB * NCORE * VOC);
}

// Round 13
// 2672.674 us; speedup vs baseline: 1.1012x; 1.1012x over previous
//
#include <hip/hip_runtime.h>
#include <hip/hip_bf16.h>
#include <math.h>

#define D 512
#define NHEAD 16
#define DK 32
#define NLAYER 16
#define FF 1024
#define VOC 32768
#define TTF 384
#define NCORE 256
#define NB 16

typedef __attribute__((ext_vector_type(8))) short bfrag;   // 8 bf16 (4 VGPRs)
typedef __attribute__((ext_vector_type(4))) float f32x4;

// ---------- async global->LDS, 16B per lane ----------
typedef __attribute__((address_space(3))) void lds_void;
typedef const __attribute__((address_space(1))) void gbl_void;
__device__ __forceinline__ void gload16(const void* g, void* l) {
    __builtin_amdgcn_global_load_lds((gbl_void*)g, (lds_void*)l, 16, 0, 0);
}

__device__ __forceinline__ float gelu_f(float v) {
    return 0.5f * v * (1.0f + erff(v * 0.70710678118654752f));
}

__device__ __forceinline__ void bf8_to_f32(uint4 u, float* v) {
    const __hip_bfloat16* t = reinterpret_cast<const __hip_bfloat16*>(&u);
    #pragma unroll
    for (int e = 0; e < 8; e++) v[e] = __bfloat162float(t[e]);
}
__device__ __forceinline__ uint4 f32_to_bf8(const float* v) {
    uint4 u; __hip_bfloat16* t = reinterpret_cast<__hip_bfloat16*>(&u);
    #pragma unroll
    for (int e = 0; e < 8; e++) t[e] = __float2bfloat16(v[e]);
    return u;
}

// ---------------- all weights f32 -> bf16 in ONE launch ----------------
__global__ __launch_bounds__(256) void cvtall_k(
    const float* s0, const float* s1, const float* s2, const float* s3,
    const float* s4, const float* s5, const float* s6, const float* s7,
    const float* s8, const float* s9, const float* s10,
    __hip_bfloat16* __restrict__ out)
{
    long long i = ((long long)blockIdx.x * 256 + threadIdx.x) * 8;
    if (i >= 52559872LL) return;
    const float* src; long long base; bool pad = false;
    if      (i < 12582912LL) { src = s0;  base = 0LL; }
    else if (i < 16777216LL) { src = s1;  base = 12582912LL; }
    else if (i < 25165824LL) { src = s2;  base = 16777216LL; }
    else if (i < 33554432LL) { src = s3;  base = 25165824LL; }
    else if (i < 50331648LL) { src = s4;  base = 33554432LL; }
    else if (i < 51118080LL) { src = s5;  base = 50331648LL; }
    else if (i < 51904512LL) { src = s6;  base = 51118080LL; }
    else if (i < 52166656LL) { src = s7;  base = 51904512LL; }
    else if (i < 52428800LL) { src = s8;  base = 52166656LL; }
    else if (i < 52494336LL) { src = s9;  base = 52428800LL; pad = true; }
    else                     { src = s10; base = 52494336LL; pad = true; }
    long long loc = i - base;
    float v[8] = {0.f,0.f,0.f,0.f,0.f,0.f,0.f,0.f};
    if (!pad || loc < 32768LL) {
        float4 a = *reinterpret_cast<const float4*>(src + loc);
        float4 b = *reinterpret_cast<const float4*>(src + loc + 4);
        v[0]=a.x; v[1]=a.y; v[2]=a.z; v[3]=a.w; v[4]=b.x; v[5]=b.y; v[6]=b.z; v[7]=b.w;
    }
    *reinterpret_cast<uint4*>(out + i) = f32_to_bf8(v);
}

// ---------------- all three embedding gathers in ONE launch ----------------
__global__ __launch_bounds__(128) void embed_all_k(
    const int* __restrict__ ids,
    const float* __restrict__ lg_sem, const float* __restrict__ lg_pos,
    const float* __restrict__ md_sem, const float* __restrict__ md_pos,
    const float* __restrict__ em_sem, const float* __restrict__ em_pos,
    __hip_bfloat16* __restrict__ lg_dst, __hip_bfloat16* __restrict__ md_dst,
    __hip_bfloat16* __restrict__ x)
{
    int bx = blockIdx.x, b = blockIdx.y, tid = threadIdx.x;
    const float *sem, *pos;
    __hip_bfloat16* outp;
    int t, idoff;
    if (bx < 512)      { t = bx;       sem = lg_sem; pos = lg_pos; idoff = 0;   outp = lg_dst + (size_t)(b * 512 + t) * D; }
    else if (bx < 768) { t = bx - 512; sem = md_sem; pos = md_pos; idoff = 512; outp = md_dst + (size_t)(b * 256 + t) * D; }
    else               { t = bx - 768; sem = em_sem; pos = em_pos; idoff = 768; outp = x + (size_t)(b * TTF + 128 + t) * D; }
    int id = ids[b * 1024 + idoff + t];
    float4 a = reinterpret_cast<const float4*>(sem + (size_t)id * D)[tid];
    float4 p = reinterpret_cast<const float4*>(pos + (size_t)t * D)[tid];
    __hip_bfloat16* o = outp + tid * 4;
    o[0] = __float2bfloat16(a.x + p.x); o[1] = __float2bfloat16(a.y + p.y);
    o[2] = __float2bfloat16(a.z + p.z); o[3] = __float2bfloat16(a.w + p.w);
}

// ---------------- bf16 MFMA GEMM: C(M,N) = A(M,K) @ W(N,K)^T + bias ----------------
// 128x128 tile, 4 waves, BK=64, double-buffered LDS, XOR-swizzled, RT row-tiles per
// block as one flattened continuous pipeline, uniform vmcnt(8).
// flags: 0=f32 out, 2=bf16+GELU, 3=bf16
// order 0: XCD-chunk row-major. order 1: col-tile-major.
__global__ __launch_bounds__(256) void mgemm_k(
    const __hip_bfloat16* __restrict__ A, const __hip_bfloat16* __restrict__ W,
    const float* __restrict__ bias, void* __restrict__ C,
    int M, int N, int K, int flags, int order, int RT)
{
    __shared__ __align__(16) __hip_bfloat16 sA[2][8192];
    __shared__ __align__(16) __hip_bfloat16 sB[2][8192];
    int tid = threadIdx.x;
    int w = tid >> 6, lane = tid & 63;
    int wr = w >> 1, wc = w & 1;

    int nbx = gridDim.x, nby = gridDim.y;
    int nwg = nbx * nby;
    int bid0 = blockIdx.y * nbx + blockIdx.x;
    int bid = bid0;
    if (nwg >= 8) {                        // bijective XCD swizzle (m204)
        int q = nwg >> 3, r = nwg & 7;
        int xcd = bid0 & 7, lb = bid0 >> 3;
        bid = (xcd < r ? xcd * (q + 1) : r * (q + 1) + (xcd - r) * q) + lb;
    }
    int bx, byg;
    if (order == 1) { bx = bid / nby; byg = bid - bx * nby; }
    else            { byg = bid / nbx; bx = bid - byg * nbx; }
    int col0 = bx * 128;

    int srow = lane >> 3;
    int scg  = (lane & 7) ^ srow;
    int cr = lane >> 4;
    int cc = lane & 15;

    auto stage = [&](int buf, int t, int k0) {
        int r0 = (byg * RT + t) * 128;
        #pragma unroll
        for (int r = 0; r < 4; r++) {
            int blk = r * 4 + w;
            const __hip_bfloat16* pa = A + (size_t)(r0 + blk * 8 + srow) * K + scg * 8 + k0;
            const __hip_bfloat16* pb = W + (size_t)(col0 + blk * 8 + srow) * K + scg * 8 + k0;
            gload16(pa, &sA[buf][blk * 512]);
            gload16(pb, &sB[buf][blk * 512]);
        }
    };

    int ksteps = K >> 6;
    int tsteps = RT * ksteps;

    stage(0, 0, 0);
    for (int t = 0; t < RT; t++) {
        int row0 = (byg * RT + t) * 128;

        f32x4 acc[4][4];
        #pragma unroll
        for (int m = 0; m < 4; m++)
            #pragma unroll
            for (int n = 0; n < 4; n++) acc[m][n] = (f32x4){0.f, 0.f, 0.f, 0.f};

        for (int kk = 0; kk < ksteps; kk++) {
            int s = t * ksteps + kk;
            int p = s & 1;
            if (s + 1 < tsteps) {
                int ns = s + 1;
                stage(p ^ 1, ns / ksteps, (ns % ksteps) << 6);
                asm volatile("s_waitcnt vmcnt(8)" ::: "memory");
            } else {
                asm volatile("s_waitcnt vmcnt(0)" ::: "memory");
            }
            __builtin_amdgcn_sched_barrier(0);
            __builtin_amdgcn_s_barrier();
            __builtin_amdgcn_sched_barrier(0);

            #pragma unroll
            for (int ks = 0; ks < 2; ks++) {
                bfrag af[4], bf[4];
                #pragma unroll
                for (int m = 0; m < 4; m++) {
                    int blk = wr * 8 + m * 2 + (cc >> 3);
                    int slot = (ks * 4 + cr) ^ (cc & 7);
                    af[m] = *reinterpret_cast<const bfrag*>(&sA[p][blk * 512 + (cc & 7) * 64 + slot * 8]);
                }
                #pragma unroll
                for (int n = 0; n < 4; n++) {
                    int blk = wc * 8 + n * 2 + (cc >> 3);
                    int slot = (ks * 4 + cr) ^ (cc & 7);
                    bf[n] = *reinterpret_cast<const bfrag*>(&sB[p][blk * 512 + (cc & 7) * 64 + slot * 8]);
                }
                #pragma unroll
                for (int m = 0; m < 4; m++)
                    #pragma unroll
                    for (int n = 0; n < 4; n++)
                        acc[m][n] = __builtin_amdgcn_mfma_f32_16x16x32_bf16(af[m], bf[n], acc[m][n], 0, 0, 0);
            }
            __builtin_amdgcn_sched_barrier(0);
            __builtin_amdgcn_s_barrier();
            __builtin_amdgcn_sched_barrier(0);
        }

        #pragma unroll
        for (int m = 0; m < 4; m++) {
            int rg = row0 + wr * 64 + m * 16 + cr * 4;
            #pragma unroll
            for (int n = 0; n < 4; n++) {
                int cg = col0 + wc * 64 + n * 16 + cc;
                float bs = bias[cg];
                #pragma unroll
                for (int j = 0; j < 4; j++) {
                    float v = acc[m][n][j] + bs;
                    size_t off = (size_t)(rg + j) * N + cg;
                    if (flags == 2)      ((__hip_bfloat16*)C)[off] = __float2bfloat16(gelu_f(v));
                    else if (flags == 3) ((__hip_bfloat16*)C)[off] = __float2bfloat16(v);
                    else                 ((float*)C)[off] = v;
                }
            }
        }
    }
}

// ---------------- layernorm, vectorized; IB/OB: 0=f32, 1=bf16 ----------------
template<int IB, int OB>
__global__ __launch_bounds__(256) void ln_k(
    const void* __restrict__ in, void* __restrict__ out,
    const float* __restrict__ g, const float* __restrict__ bt,
    int rpb, int in_stride, int in_off, int out_stride, int out_off)
{
    int r = blockIdx.x * 4 + (threadIdx.x >> 6);
    int b = r / rpb, t = r % rpb;
    size_t irow = (size_t)(b * in_stride + in_off + t) * D;
    size_t orow = (size_t)(b * out_stride + out_off + t) * D;
    int c0 = (threadIdx.x & 63) * 8;
    float v[8];
    if (IB) {
        bf8_to_f32(*reinterpret_cast<const uint4*>((const __hip_bfloat16*)in + irow + c0), v);
    } else {
        float4 a = *reinterpret_cast<const float4*>((const float*)in + irow + c0);
        float4 bq = *reinterpret_cast<const float4*>((const float*)in + irow + c0 + 4);
        v[0]=a.x; v[1]=a.y; v[2]=a.z; v[3]=a.w; v[4]=bq.x; v[5]=bq.y; v[6]=bq.z; v[7]=bq.w;
    }
    float s = 0.f;
    #pragma unroll
    for (int e = 0; e < 8; e++) s += v[e];
    #pragma unroll
    for (int off = 32; off; off >>= 1) s += __shfl_xor(s, off);
    float mu = s * (1.f / 512.f);
    float vs = 0.f;
    #pragma unroll
    for (int e = 0; e < 8; e++) { float d = v[e] - mu; vs += d * d; }
    #pragma unroll
    for (int off = 32; off; off >>= 1) vs += __shfl_xor(vs, off);
    float rstd = rsqrtf(vs * (1.f / 512.f) + 1e-5f);
    float y[8];
    #pragma unroll
    for (int e = 0; e < 8; e++) y[e] = (v[e] - mu) * rstd * g[c0 + e] + bt[c0 + e];
    if (OB) {
        *reinterpret_cast<uint4*>((__hip_bfloat16*)out + orow + c0) = f32_to_bf8(y);
    } else {
        *reinterpret_cast<float4*>((float*)out + orow + c0)     = make_float4(y[0], y[1], y[2], y[3]);
        *reinterpret_cast<float4*>((float*)out + orow + c0 + 4) = make_float4(y[4], y[5], y[6], y[7]);
    }
}

// ---------------- fused residual add + layernorm ----------------
template<int WRITE_H>
__global__ __launch_bounds__(256) void res_ln_k(
    const __hip_bfloat16* __restrict__ delta, __hip_bfloat16* __restrict__ x,
    const float* __restrict__ g, const float* __restrict__ bt,
    __hip_bfloat16* __restrict__ h)
{
    int r = blockIdx.x * 4 + (threadIdx.x >> 6);
    int c0 = (threadIdx.x & 63) * 8;
    size_t row = (size_t)r * D + c0;
    float v[8], dv[8];
    bf8_to_f32(*reinterpret_cast<const uint4*>(x + row), v);
    bf8_to_f32(*reinterpret_cast<const uint4*>(delta + row), dv);
    #pragma unroll
    for (int e = 0; e < 8; e++) v[e] += dv[e];
    *reinterpret_cast<uint4*>(x + row) = f32_to_bf8(v);
    if (WRITE_H) {
        float s = 0.f;
        #pragma unroll
        for (int e = 0; e < 8; e++) s += v[e];
        #pragma unroll
        for (int off = 32; off; off >>= 1) s += __shfl_xor(s, off);
        float mu = s * (1.f / 512.f);
        float vs = 0.f;
        #pragma unroll
        for (int e = 0; e < 8; e++) { float d = v[e] - mu; vs += d * d; }
        #pragma unroll
        for (int off = 32; off; off >>= 1) vs += __shfl_xor(vs, off);
        float rstd = rsqrtf(vs * (1.f / 512.f) + 1e-5f);
        float y[8];
        #pragma unroll
        for (int e = 0; e < 8; e++) y[e] = (v[e] - mu) * rstd * g[c0 + e] + bt[c0 + e];
        *reinterpret_cast<uint4*>(h + row) = f32_to_bf8(y);
    }
}

// ---------------- fused MFMA causal attention (core layers) ----------------
// Split 2 ways per (h,b): part 0 = q-tiles 0..15 (keys 0..255), part 1 = q-tiles 16..23.
__global__ __launch_bounds__(512) void fattn_k(
    const __hip_bfloat16* __restrict__ qkv, __hip_bfloat16* __restrict__ o)
{
    __shared__ __align__(16) __hip_bfloat16 Kl[24 * 512];
    __shared__ __align__(16) __hip_bfloat16 Vl[24 * 512];
    __shared__ __align__(16) __hip_bfloat16 Pl[8 * 512];
    int h = blockIdx.x, b = blockIdx.y, part = blockIdx.z;
    int tid = threadIdx.x, w = tid >> 6, l = tid & 63;
    const size_t base = (size_t)b * TTF * 1536 + h * DK;

    int niter = part ? 3 : 2;
    for (int it = 0; it < niter; it++) {
        int item = it * 512 + tid;
        int key = item >> 2, dg = item & 3;
        uint4 k4 = *reinterpret_cast<const uint4*>(qkv + base + (size_t)key * 1536 + 512 + dg * 8);
        *reinterpret_cast<uint4*>(&Kl[((key >> 4) * 64 + dg * 16 + (key & 15)) * 8]) = k4;
        uint4 v4 = *reinterpret_cast<const uint4*>(qkv + base + (size_t)key * 1536 + 1024 + dg * 8);
        const ushort* ve = reinterpret_cast<const ushort*>(&v4);
        #pragma unroll
        for (int e = 0; e < 8; e++) {
            int dk = dg * 8 + e;
            int f = (((key & 31) >> 3) << 4) | (dk & 15);
            int idx = (((key >> 5) << 1) + (dk >> 4)) * 512 + f * 8 + (key & 7);
            reinterpret_cast<ushort*>(Vl)[idx] = ve[e];
        }
    }
    __syncthreads();

    const float sc = 0.17677669529663687f;
    __hip_bfloat16* pw = Pl + w * 512;

    int niq = part ? 1 : 2;
    for (int iq = 0; iq < niq; iq++) {
        int qt = part ? (16 + w) : (iq == 0 ? w : 15 - w);
        int q0 = qt * 16;
        bfrag qf = *reinterpret_cast<const bfrag*>(qkv + base + (size_t)(q0 + (l & 15)) * 1536 + (l >> 4) * 8);
        f32x4 oa0 = (f32x4){0.f, 0.f, 0.f, 0.f};
        f32x4 oa1 = (f32x4){0.f, 0.f, 0.f, 0.f};
        float mrun[4], lrun[4];
        #pragma unroll
        for (int jj = 0; jj < 4; jj++) { mrun[jj] = -3.0e38f; lrun[jj] = 0.f; }
        int ksmax = (q0 + 15) >> 5;

        for (int ks = 0; ks <= ksmax; ks++) {
            bfrag kf0 = *reinterpret_cast<const bfrag*>(&Kl[(ks * 2 + 0) * 512 + l * 8]);
            bfrag kf1 = *reinterpret_cast<const bfrag*>(&Kl[(ks * 2 + 1) * 512 + l * 8]);
            f32x4 z = (f32x4){0.f, 0.f, 0.f, 0.f};
            __builtin_amdgcn_s_setprio(1);
            f32x4 s0 = __builtin_amdgcn_mfma_f32_16x16x32_bf16(qf, kf0, z, 0, 0, 0);
            f32x4 s1 = __builtin_amdgcn_mfma_f32_16x16x32_bf16(qf, kf1, z, 0, 0, 0);
            __builtin_amdgcn_s_setprio(0);
            if (ks == ksmax) {
                #pragma unroll
                for (int jj = 0; jj < 4; jj++) {
                    int q = q0 + ((l >> 4) << 2) + jj;
                    if (ks * 32 + (l & 15) > q)      s0[jj] = -3.0e38f;
                    if (ks * 32 + 16 + (l & 15) > q) s1[jj] = -3.0e38f;
                }
            }
            float p0[4], p1[4], ps[4];
            #pragma unroll
            for (int jj = 0; jj < 4; jj++) {
                float sm = fmaxf(s0[jj], s1[jj]);
                #pragma unroll
                for (int off = 1; off <= 8; off <<= 1) sm = fmaxf(sm, __shfl_xor(sm, off));
                float mnew = fmaxf(mrun[jj], sm);
                float f = __expf((mrun[jj] - mnew) * sc);
                mrun[jj] = mnew;
                lrun[jj] *= f;
                oa0[jj] *= f; oa1[jj] *= f;
                p0[jj] = __expf((s0[jj] - mnew) * sc);
                p1[jj] = __expf((s1[jj] - mnew) * sc);
                ps[jj] = p0[jj] + p1[jj];
            }
            #pragma unroll
            for (int jj = 0; jj < 4; jj++) {
                float t = ps[jj];
                #pragma unroll
                for (int off = 1; off <= 8; off <<= 1) t += __shfl_xor(t, off);
                lrun[jj] += t;
            }
            #pragma unroll
            for (int jj = 0; jj < 4; jj++) {
                int ql = ((l >> 4) << 2) + jj;
                int kl0 = l & 15, kl1 = 16 + (l & 15);
                pw[((kl0 >> 3) * 16 + ql) * 8 + (kl0 & 7)] = __float2bfloat16(p0[jj]);
                pw[((kl1 >> 3) * 16 + ql) * 8 + (kl1 & 7)] = __float2bfloat16(p1[jj]);
            }
            bfrag pf  = *reinterpret_cast<const bfrag*>(&pw[l * 8]);
            bfrag vf0 = *reinterpret_cast<const bfrag*>(&Vl[(ks * 2 + 0) * 512 + l * 8]);
            bfrag vf1 = *reinterpret_cast<const bfrag*>(&Vl[(ks * 2 + 1) * 512 + l * 8]);
            __builtin_amdgcn_s_setprio(1);
            oa0 = __builtin_amdgcn_mfma_f32_16x16x32_bf16(pf, vf0, oa0, 0, 0, 0);
            oa1 = __builtin_amdgcn_mfma_f32_16x16x32_bf16(pf, vf1, oa1, 0, 0, 0);
            __builtin_amdgcn_s_setprio(0);
        }
        #pragma unroll
        for (int jj = 0; jj < 4; jj++) {
            float inv = 1.0f / lrun[jj];
            int q = q0 + ((l >> 4) << 2) + jj;
            size_t orow = ((size_t)b * TTF + q) * D + h * DK;
            o[orow + (l & 15)]      = __float2bfloat16(oa0[jj] * inv);
            o[orow + 16 + (l & 15)] = __float2bfloat16(oa1[jj] * inv);
        }
    }
}

// ---------------- summarizer cross-attention: MFMA, block per (h,b), 4 waves ----------------
template<int TLEN>
__global__ __launch_bounds__(256) void sattn_k(
    const __hip_bfloat16* __restrict__ q, const __hip_bfloat16* __restrict__ kv,
    __hip_bfloat16* __restrict__ o)
{
    __shared__ __align__(16) __hip_bfloat16 Kl[(TLEN / 16) * 512];
    __shared__ __align__(16) __hip_bfloat16 Vl[(TLEN / 16) * 512];
    __shared__ __align__(16) __hip_bfloat16 Pl[4 * 512];
    int h = blockIdx.x, b = blockIdx.y;
    int tid = threadIdx.x, w = tid >> 6, l = tid & 63;

    for (int it = 0; it < TLEN / 64; it++) {
        int item = it * 256 + tid;
        int key = item >> 2, dg = item & 3;
        const __hip_bfloat16* kr = kv + (size_t)(b * TLEN + key) * 1024 + h * DK + dg * 8;
        uint4 k4 = *reinterpret_cast<const uint4*>(kr);
        *reinterpret_cast<uint4*>(&Kl[((key >> 4) * 64 + dg * 16 + (key & 15)) * 8]) = k4;
        uint4 v4 = *reinterpret_cast<const uint4*>(kr + 512);
        const ushort* ve = reinterpret_cast<const ushort*>(&v4);
        #pragma unroll
        for (int e = 0; e < 8; e++) {
            int dk = dg * 8 + e;
            int f = (((key & 31) >> 3) << 4) | (dk & 15);
            int idx = (((key >> 5) << 1) + (dk >> 4)) * 512 + f * 8 + (key & 7);
            reinterpret_cast<ushort*>(Vl)[idx] = ve[e];
        }
    }
    __syncthreads();

    const float sc = 0.17677669529663687f;
    __hip_bfloat16* pw = Pl + w * 512;
    int q0 = w * 16;
    bfrag qf = *reinterpret_cast<const bfrag*>(q + (size_t)(q0 + (l & 15)) * D + h * DK + (l >> 4) * 8);
    f32x4 oa0 = (f32x4){0.f, 0.f, 0.f, 0.f};
    f32x4 oa1 = (f32x4){0.f, 0.f, 0.f, 0.f};
    float mrun[4], lrun[4];
    #pragma unroll
    for (int jj = 0; jj < 4; jj++) { mrun[jj] = -3.0e38f; lrun[jj] = 0.f; }

    for (int ks = 0; ks < TLEN / 32; ks++) {
        bfrag kf0 = *reinterpret_cast<const bfrag*>(&Kl[(ks * 2 + 0) * 512 + l * 8]);
        bfrag kf1 = *reinterpret_cast<const bfrag*>(&Kl[(ks * 2 + 1) * 512 + l * 8]);
        f32x4 z = (f32x4){0.f, 0.f, 0.f, 0.f};
        __builtin_amdgcn_s_setprio(1);
        f32x4 s0 = __builtin_amdgcn_mfma_f32_16x16x32_bf16(qf, kf0, z, 0, 0, 0);
        f32x4 s1 = __builtin_amdgcn_mfma_f32_16x16x32_bf16(qf, kf1, z, 0, 0, 0);
        __builtin_amdgcn_s_setprio(0);
        float p0[4], p1[4], ps[4];
        #pragma unroll
        for (int jj = 0; jj < 4; jj++) {
            float sm = fmaxf(s0[jj], s1[jj]);
            #pragma unroll
            for (int off = 1; off <= 8; off <<= 1) sm = fmaxf(sm, __shfl_xor(sm, off));
            float mnew = fmaxf(mrun[jj], sm);
            float f = __expf((mrun[jj] - mnew) * sc);
            mrun[jj] = mnew;
            lrun[jj] *= f;
            oa0[jj] *= f; oa1[jj] *= f;
            p0[jj] = __expf((s0[jj] - mnew) * sc);
            p1[jj] = __expf((s1[jj] - mnew) * sc);
            ps[jj] = p0[jj] + p1[jj];
        }
        #pragma unroll
        for (int jj = 0; jj < 4; jj++) {
            float t = ps[jj];
            #pragma unroll
            for (int off = 1; off <= 8; off <<= 1) t += __shfl_xor(t, off);
            lrun[jj] += t;
        }
        #pragma unroll
        for (int jj = 0; jj < 4; jj++) {
            int ql = ((l >> 4) << 2) + jj;
            int kl0 = l & 15, kl1 = 16 + (l & 15);
            pw[((kl0 >> 3) * 16 + ql) * 8 + (kl0 & 7)] = __float2bfloat16(p0[jj]);
            pw[((kl1 >> 3) * 16 + ql) * 8 + (kl1 & 7)] = __float2bfloat16(p1[jj]);
        }
        bfrag pf  = *reinterpret_cast<const bfrag*>(&pw[l * 8]);
        bfrag vf0 = *reinterpret_cast<const bfrag*>(&Vl[(ks * 2 + 0) * 512 + l * 8]);
        bfrag vf1 = *reinterpret_cast<const bfrag*>(&Vl[(ks * 2 + 1) * 512 + l * 8]);
        __builtin_amdgcn_s_setprio(1);
        oa0 = __builtin_amdgcn_mfma_f32_16x16x32_bf16(pf, vf0, oa0, 0, 0, 0);
        oa1 = __builtin_amdgcn_mfma_f32_16x16x32_bf16(pf, vf1, oa1, 0, 0, 0);
        __builtin_amdgcn_s_setprio(0);
    }
    #pragma unroll
    for (int jj = 0; jj < 4; jj++) {
        float inv = 1.0f / lrun[jj];
        int qi = q0 + ((l >> 4) << 2) + jj;
        size_t orow = ((size_t)b * 64 + qi) * D + h * DK;
        o[orow + (l & 15)]      = __float2bfloat16(oa0[jj] * inv);
        o[orow + 16 + (l & 15)] = __float2bfloat16(oa1[jj] * inv);
    }
}

// ---------------- tgt copy ----------------
__global__ __launch_bounds__(256) void tgt_k(const int* __restrict__ tids, float* __restrict__ out)
{
    int i = blockIdx.x * 256 + threadIdx.x;
    int b = i >> 8, c = i & 255;
    out[i] = (float)tids[b * 1024 + 768 + c];
}

extern "C" void kernel_launch(void* const* d_in, const int* in_sizes, int n_in,
                              void* d_out, int out_size, void* d_ws, size_t ws_size,
                              hipStream_t stream) {
    (void)in_sizes; (void)n_in; (void)out_size; (void)ws_size;
    const int*   input_ids  = (const int*)  d_in[0];
    const int*   target_ids = (const int*)  d_in[1];
    const float* emb_sem    = (const float*)d_in[2];
    const float* emb_pos    = (const float*)d_in[3];
    const float* lg_sem     = (const float*)d_in[4];
    const float* lg_pos     = (const float*)d_in[5];
    const float* lg_inw     = (const float*)d_in[6];
    const float* lg_inb     = (const float*)d_in[7];
    const float* lg_outw    = (const float*)d_in[8];
    const float* lg_outb    = (const float*)d_in[9];
    const float* lg_tok     = (const float*)d_in[10];
    const float* lg_lng     = (const float*)d_in[11];
    const float* lg_lnb     = (const float*)d_in[12];
    const float* md_sem     = (const float*)d_in[13];
    const float* md_pos     = (const float*)d_in[14];
    const float* md_inw     = (const float*)d_in[15];
    const float* md_inb     = (const float*)d_in[16];
    const float* md_outw    = (const float*)d_in[17];
    const float* md_outb    = (const float*)d_in[18];
    const float* md_tok     = (const float*)d_in[19];
    const float* md_lng     = (const float*)d_in[20];
    const float* md_lnb     = (const float*)d_in[21];
    const float* qkv_w      = (const float*)d_in[22];
    const float* qkv_b      = (const float*)d_in[23];
    const float* wo_w       = (const float*)d_in[24];
    const float* wo_b       = (const float*)d_in[25];
    const float* ln1_g      = (const float*)d_in[26];
    const float* ln1_b      = (const float*)d_in[27];
    const float* ln2_g      = (const float*)d_in[28];
    const float* ln2_b      = (const float*)d_in[29];
    const float* ff1_w      = (const float*)d_in[30];
    const float* ff1_b      = (const float*)d_in[31];
    const float* ff2_w      = (const float*)d_in[32];
    const float* ff2_b      = (const float*)d_in[33];
    const float* hd_lng     = (const float*)d_in[34];
    const float* hd_lnb     = (const float*)d_in[35];
    const float* hd_w       = (const float*)d_in[36];
    const float* hd_b       = (const float*)d_in[37];

    // ---- workspace layout (bf16 unless noted) ----
    __hip_bfloat16* x_bf   = (__hip_bfloat16*)d_ws;            // 3,145,728 (residual stream)
    __hip_bfloat16* h_bf   = x_bf   + 3145728;                 // 3,145,728
    __hip_bfloat16* d_bf   = h_bf   + 3145728;                 // 3,145,728 (GEMM delta)
    __hip_bfloat16* a_bf   = d_bf   + 3145728;                 // 6,291,456 (lg embeds | md embeds @+4194304; later attn out)
    __hip_bfloat16* qkv_bf = a_bf   + 6291456;                 // 9,437,184
    __hip_bfloat16* sumo_bf= qkv_bf + 9437184;                 // 524,288
    __hip_bfloat16* w_qkv  = sumo_bf+ 524288;                  // 12,582,912   -- cvtall region start
    __hip_bfloat16* w_wo   = w_qkv  + 12582912;                // 4,194,304
    __hip_bfloat16* w_ff1  = w_wo   + 4194304;                 // 8,388,608
    __hip_bfloat16* w_ff2  = w_ff1  + 8388608;                 // 8,388,608
    __hip_bfloat16* w_hd   = w_ff2  + 8388608;                 // 16,777,216
    __hip_bfloat16* w_lgin = w_hd   + 16777216;                // 786,432
    __hip_bfloat16* w_mdin = w_lgin + 786432;                  // 786,432
    __hip_bfloat16* w_lgout= w_mdin + 786432;                  // 262,144
    __hip_bfloat16* w_mdout= w_lgout+ 262144;                  // 262,144
    __hip_bfloat16* tok_lg = w_mdout+ 262144;                  // 65,536 (32768 valid + zero pad)
    __hip_bfloat16* tok_md = tok_lg + 65536;                   // 65,536       -- cvtall region end
    __hip_bfloat16* q_bf   = tok_md + 65536;                   // 65,536
    float* so2 = (float*)(q_bf + 65536);                       // 524,288 f32

    // ---- all weight conversions in one launch ----
    cvtall_k<<<25664, 256, 0, stream>>>(qkv_w, wo_w, ff1_w, ff2_w, hd_w,
                                        lg_inw, md_inw, lg_outw, md_outw,
                                        lg_tok, md_tok, w_qkv);

    // ---- all embeddings in one launch (lg -> a_bf, md -> a_bf+4194304, core -> x) ----
    embed_all_k<<<dim3(1024, NB), 128, 0, stream>>>(input_ids,
        lg_sem, lg_pos, md_sem, md_pos, emb_sem, emb_pos,
        a_bf, a_bf + 4194304, x_bf);

    // ======== summarizer LG (tlen=512) ========
    mgemm_k<<<dim3(8, 64), 256, 0, stream>>>(a_bf, w_lgin + 512 * 512, lg_inb + 512, qkv_bf, 8192, 1024, 512, 3, 0, 1);
    mgemm_k<<<dim3(4, 1), 256, 0, stream>>>(tok_lg, w_lgin, lg_inb, q_bf, 128, 512, 512, 3, 0, 1);
    sattn_k<512><<<dim3(NHEAD, NB), 256, 0, stream>>>(q_bf, qkv_bf, sumo_bf);
    mgemm_k<<<dim3(4, 8), 256, 0, stream>>>(sumo_bf, w_lgout, lg_outb, so2, 1024, 512, 512, 0, 0, 1);
    ln_k<0, 1><<<256, 256, 0, stream>>>(so2, x_bf, lg_lng, lg_lnb, 64, 64, 0, TTF, 0);

    // ======== summarizer MD (tlen=256) ========
    mgemm_k<<<dim3(8, 32), 256, 0, stream>>>(a_bf + 4194304, w_mdin + 512 * 512, md_inb + 512, qkv_bf, 4096, 1024, 512, 3, 0, 1);
    mgemm_k<<<dim3(4, 1), 256, 0, stream>>>(tok_md, w_mdin, md_inb, q_bf, 128, 512, 512, 3, 0, 1);
    sattn_k<256><<<dim3(NHEAD, NB), 256, 0, stream>>>(q_bf, qkv_bf, sumo_bf);
    mgemm_k<<<dim3(4, 8), 256, 0, stream>>>(sumo_bf, w_mdout, md_outb, so2, 1024, 512, 512, 0, 0, 1);
    ln_k<0, 1><<<256, 256, 0, stream>>>(so2, x_bf, md_lng, md_lnb, 64, 64, 0, TTF, 64);

    // ======== 16 transformer layers (bf16 residual, fused res+LN) ========
    ln_k<1, 1><<<1536, 256, 0, stream>>>(x_bf, h_bf, ln1_g, ln1_b, TTF, TTF, 0, TTF, 0);
    for (int l = 0; l < NLAYER; l++) {
        mgemm_k<<<dim3(12, 48), 256, 0, stream>>>(h_bf, w_qkv + (size_t)l * 1536 * 512, qkv_b + l * 1536, qkv_bf, 6144, 1536, 512, 3, 0, 1);
        fattn_k<<<dim3(NHEAD, NB, 2), 512, 0, stream>>>(qkv_bf, a_bf);
        mgemm_k<<<dim3(4, 48), 256, 0, stream>>>(a_bf, w_wo + (size_t)l * 512 * 512, wo_b + l * D, d_bf, 6144, 512, 512, 3, 0, 1);
        res_ln_k<1><<<1536, 256, 0, stream>>>(d_bf, x_bf, ln2_g + l * D, ln2_b + l * D, h_bf);
        mgemm_k<<<dim3(8, 48), 256, 0, stream>>>(h_bf, w_ff1 + (size_t)l * 1024 * 512, ff1_b + l * FF, a_bf, 6144, 1024, 512, 2, 0, 1);
        mgemm_k<<<dim3(4, 48), 256, 0, stream>>>(a_bf, w_ff2 + (size_t)l * 512 * 1024, ff2_b + l * D, d_bf, 6144, 512, 1024, 3, 0, 1);
        if (l < NLAYER - 1) {
            res_ln_k<1><<<1536, 256, 0, stream>>>(d_bf, x_bf, ln1_g + (size_t)(l + 1) * D, ln1_b + (size_t)(l + 1) * D, h_bf);
        } else {
            res_ln_k<0><<<1536, 256, 0, stream>>>(d_bf, x_bf, hd_lng, hd_lnb, h_bf);
        }
    }

    // ======== head: LN + col-tile-major GEMM, RT=8 continuous pipeline ========
    ln_k<1, 1><<<1024, 256, 0, stream>>>(x_bf, h_bf, hd_lng, hd_lnb, NCORE, TTF, 128, NCORE, 0);
    float* logits = (float*)d_out;
    mgemm_k<<<dim3(256, 4), 256, 0, stream>>>(h_bf, w_hd, hd_b, logits, 4096, VOC, 512, 0, 1, 8);
    tgt_k<<<16, 256, 0, stream>>>(target_ids, logits + (size_t)NB * NCORE * VOC);
}